// Round 1
// 375.706 us; speedup vs baseline: 1.0499x; 1.0499x over previous
//
#include <hip/hip_runtime.h>
#include <hip/hip_bf16.h>

// ObjectDecoder: out[b,o,a,p,k] = sum_d x[b,o,d] * W[o,a,p,d,k] + bias[o,a,p,k]
// B=16384, N_OBJ=16, N_ATTR=4, N_PARAM=2, DIM_IN=256, D_ATTR=8
// => 16 GEMMs of M=16384, N=64, K=256.
// Memory-bound: 268MB x + 67MB out + 1MB W => ~53us floor at 6.3 TB/s.
// Timed harness region also contains ~2x161us of 1-GiB poison fills (rocprof:
// top-5 dispatches are fillBufferAligned), so kernel-only is ~72us of the
// 394us total. This round attacks the kernel's ~19us gap to its roofline:
//  - __launch_bounds__(256,4): cap VGPR<=128 -> 4 waves/SIMD (was possibly 2),
//    doubling resident waves for HBM latency hiding. Live-reg audit ~100.
//  - nontemporal loads on x / stores on out: single-use streams, evict-first
//    in L2 so the 268MB x stream stops thrashing the 32MB L2 (W stays hot).

#define NOBJ   16
#define DIMIN  256
#define NCOL   64              // N_ATTR*N_PARAM*D_ATTR
#define XROW   (NOBJ*DIMIN)    // 4096 floats between consecutive b rows of x
#define OROW   (NOBJ*NCOL)     // 1024 floats between consecutive b rows of out
#define WOBJ   (NCOL*DIMIN)    // 16384 elems of W per object

typedef __attribute__((ext_vector_type(8))) short short8;   // 8 x bf16
typedef __attribute__((ext_vector_type(4))) float floatx4;  // MFMA C/D + vec loads

// fp32 -> bf16 bits, round-to-nearest-even, branch-free (inputs finite).
static __device__ __forceinline__ short f2bf(float f) {
    unsigned u = __builtin_bit_cast(unsigned, f);
    u += 0x7fffu + ((u >> 16) & 1u);
    return (short)(u >> 16);
}

static __device__ __forceinline__ floatx4 ntld4(const float* p) {
    return __builtin_nontemporal_load((const floatx4*)p);
}

// grid = 16 objects * 64 blocks = 1024; block = 256 threads (4 waves).
// Block (o, g) handles rows [g*256, g*256+256) of object o.
// Wave w: rows g*256 + w*64 .. +64, as 2 supertiles of M=32.
__global__ __launch_bounds__(256, 4) void obj_decoder(
    const float* __restrict__ x,
    const float* __restrict__ W,
    const float* __restrict__ bias,
    float* __restrict__ out)
{
    __shared__ short ldsB[WOBJ];      // 32 KB: W_o as bf16 in MFMA B-fragment order

    const int tid = threadIdx.x;
    const int bx  = blockIdx.x;
    const int o   = bx >> 6;          // 64 blocks per object
    const int g   = bx & 63;

    // ---- Stage W_o (fp32) -> LDS (bf16), MFMA B-operand fragment order ----
    // W flat within object: e = (ap*256 + d)*8 + k, ap=a*2+p, k=col-in-attr.
    // Col n = ap*8 + k. Fragment (kt,nt): lane l holds
    // B[d = kt*32 + (l>>4)*8 + j][n = nt*16 + (l&15)], j=0..7 contiguous
    // => LDS idx = ((kt*4+nt)*64 + l)*8 + j  (ds_read_b128 per fragment).
    const float* Wo = W + o * WOBJ;
    #pragma unroll
    for (int r = 0; r < 8; ++r) {
        int gbase = (r * 256 + tid) * 8;   // 8 consecutive W elems: ap=r, d=tid, k=0..7
        floatx4 f0 = *(const floatx4*)(Wo + gbase);
        floatx4 f1 = *(const floatx4*)(Wo + gbase + 4);
        const int d  = tid;
        const int kt = d >> 5, quad = (d >> 3) & 3, j = d & 7;
        const int nt = r >> 1;
        // n = r*8 + k  =>  n&15 = (r&1)*8 + k,  lane l = quad*16 + (n&15)
        const int base = ((kt * 4 + nt) * 64 + quad * 16 + (r & 1) * 8) * 8 + j;
        float fv[8] = {f0[0], f0[1], f0[2], f0[3], f1[0], f1[1], f1[2], f1[3]};
        #pragma unroll
        for (int k = 0; k < 8; ++k)
            ldsB[base + k * 8] = f2bf(fv[k]);
    }

    const int lane = tid & 63;
    const int w    = tid >> 6;
    const int rl   = lane & 15;       // row within A tile / col within C
    const int quad = lane >> 4;

    // bias: each lane needs cols nt*16 + rl (same for every row)
    float bv[4];
    #pragma unroll
    for (int nt = 0; nt < 4; ++nt)
        bv[nt] = bias[o * NCOL + nt * 16 + rl];

    __syncthreads();

    #pragma unroll
    for (int st = 0; st < 2; ++st) {
        const int m0 = g * 256 + w * 64 + st * 32;
        // A fragment: lane holds A[m = rl][k = quad*8 + j] -> 32B contiguous fp32
        const float* a0p = x + (size_t)(m0 + rl) * XROW + o * DIMIN + quad * 8;
        const float* a1p = a0p + (size_t)16 * XROW;

        floatx4 acc[2][4] = {};   // [m-tile][n-tile]

        #pragma unroll
        for (int kt = 0; kt < 8; ++kt) {
            floatx4 u0 = ntld4(a0p + kt * 32);
            floatx4 u1 = ntld4(a0p + kt * 32 + 4);
            floatx4 u2 = ntld4(a1p + kt * 32);
            floatx4 u3 = ntld4(a1p + kt * 32 + 4);
            short8 a0 = {f2bf(u0[0]), f2bf(u0[1]), f2bf(u0[2]), f2bf(u0[3]),
                         f2bf(u1[0]), f2bf(u1[1]), f2bf(u1[2]), f2bf(u1[3])};
            short8 a1 = {f2bf(u2[0]), f2bf(u2[1]), f2bf(u2[2]), f2bf(u2[3]),
                         f2bf(u3[0]), f2bf(u3[1]), f2bf(u3[2]), f2bf(u3[3])};
            #pragma unroll
            for (int nt = 0; nt < 4; ++nt) {
                short8 bf = *(const short8*)(&ldsB[((kt * 4 + nt) * 64 + lane) * 8]);
                acc[0][nt] = __builtin_amdgcn_mfma_f32_16x16x32_bf16(a0, bf, acc[0][nt], 0, 0, 0);
                acc[1][nt] = __builtin_amdgcn_mfma_f32_16x16x32_bf16(a1, bf, acc[1][nt], 0, 0, 0);
            }
        }

        // Epilogue: C/D layout col = lane&15, row = quad*4 + reg; fp32 out.
        #pragma unroll
        for (int mi = 0; mi < 2; ++mi) {
            #pragma unroll
            for (int reg = 0; reg < 4; ++reg) {
                const int row = m0 + mi * 16 + quad * 4 + reg;
                float* op = out + (size_t)row * OROW + o * NCOL + rl;
                #pragma unroll
                for (int nt = 0; nt < 4; ++nt)
                    __builtin_nontemporal_store(acc[mi][nt][reg] + bv[nt], op + nt * 16);
            }
        }
    }
}

extern "C" void kernel_launch(void* const* d_in, const int* in_sizes, int n_in,
                              void* d_out, int out_size, void* d_ws, size_t ws_size,
                              hipStream_t stream) {
    const float* x = (const float*)d_in[0];
    const float* W = (const float*)d_in[1];
    const float* b = (const float*)d_in[2];
    float* out = (float*)d_out;
    obj_decoder<<<dim3(1024), dim3(256), 0, stream>>>(x, W, b, out);
}